// Round 9
// baseline (208.533 us; speedup 1.0000x reference)
//
#include <hip/hip_runtime.h>

#define IN_CH 16
#define OUT_CH 16
#define EDGE_FEAT 32
#define HIDDEN 128
#define WROW 256          // IN_CH*OUT_CH
#define FN_FPB 8          // filters per block in filter-net kernel

// f16 weight row layout (512 B): 32 chunks of 16 B.
// chunk (u*4 + j), u in [0,8), j in [0,4): dword c (c in [0,4)) holds the
// f16 pair ( w[2u][4j+c] , w[2u+1][4j+c] ) — pairs run along the input
// channel so one v_dot2_f32_f16 consumes both.
// Edge lane j loads chunks {u*4+j}; the 4 lanes of an edge cover one 64 B
// line per u.

typedef __fp16 half2_v __attribute__((ext_vector_type(2)));
typedef unsigned uvec4 __attribute__((ext_vector_type(4)));
typedef float fvec4 __attribute__((ext_vector_type(4)));

__device__ __forceinline__ unsigned pk_f16(float lo, float hi) {
  half2_v h = __builtin_amdgcn_cvt_pkrtz(lo, hi);
  return __builtin_bit_cast(unsigned, h);
}

__device__ __forceinline__ float dot2(unsigned wpair, half2_v xp, float acc) {
  half2_v w = __builtin_bit_cast(half2_v, wpair);
#if __has_builtin(__builtin_amdgcn_fdot2)
  return __builtin_amdgcn_fdot2(xp, w, acc, false);
#else
  acc = fmaf((float)xp[0], (float)w[0], acc);
  return fmaf((float)xp[1], (float)w[1], acc);
#endif
}

// ---------------- Kernel 1: filter net (f16 pair-layout output) -------------
__global__ __launch_bounds__(256) void filter_net_kernel(
    const float* __restrict__ ef, const float* __restrict__ W1,
    const float* __restrict__ b1, const float* __restrict__ W2,
    const float* __restrict__ b2, unsigned short* __restrict__ weights,
    float* __restrict__ zero_base, int nzero4) {
  const int t = threadIdx.x;
  const int f0 = blockIdx.x * FN_FPB;

  // fused zeroing of sums+deg
  for (int gid = blockIdx.x * 256 + t; gid < nzero4; gid += gridDim.x * 256)
    ((float4*)zero_base)[gid] = make_float4(0.f, 0.f, 0.f, 0.f);

  __shared__ float ef_s[FN_FPB * EDGE_FEAT];  // 256 floats
  __shared__ float h_s[FN_FPB][HIDDEN];       // 1024 floats
  ef_s[t] = ef[f0 * EDGE_FEAT + t];
  __syncthreads();

  // stage 1: 1024 h values, 4 per thread.
  #pragma unroll
  for (int r = 0; r < 4; ++r) {
    const int idx = t + r * 256;
    const int fi = idx >> 7;
    const int hi = idx & (HIDDEN - 1);
    float a = b1[hi];
    #pragma unroll
    for (int k = 0; k < EDGE_FEAT; ++k)
      a = fmaf(ef_s[fi * EDGE_FEAT + k], W1[k * HIDDEN + hi], a);
    h_s[fi][hi] = a > 0.f ? a : 0.f;
  }
  __syncthreads();

  const int fslot = t >> 5;
  const int combo = t & 31;
  const int u = combo >> 2;
  const int jo = combo & 3;
  const int colLo = 32 * u + 4 * jo;   // out col base for i = 2u
  const int colHi = colLo + 16;        // for i = 2u+1

  float4 aLo = *(const float4*)(b2 + colLo);
  float4 aHi = *(const float4*)(b2 + colHi);
  const float* __restrict__ hrow = h_s[fslot];
  #pragma unroll 4
  for (int k = 0; k < HIDDEN; ++k) {
    const float4 wLo = *(const float4*)(W2 + (size_t)k * WROW + colLo);
    const float4 wHi = *(const float4*)(W2 + (size_t)k * WROW + colHi);
    const float hv = hrow[k];
    aLo.x = fmaf(hv, wLo.x, aLo.x);
    aLo.y = fmaf(hv, wLo.y, aLo.y);
    aLo.z = fmaf(hv, wLo.z, aLo.z);
    aLo.w = fmaf(hv, wLo.w, aLo.w);
    aHi.x = fmaf(hv, wHi.x, aHi.x);
    aHi.y = fmaf(hv, wHi.y, aHi.y);
    aHi.z = fmaf(hv, wHi.z, aHi.z);
    aHi.w = fmaf(hv, wHi.w, aHi.w);
  }

  uint4 st;
  st.x = pk_f16(aLo.x, aHi.x);
  st.y = pk_f16(aLo.y, aHi.y);
  st.z = pk_f16(aLo.z, aHi.z);
  st.w = pk_f16(aLo.w, aHi.w);
  *(uint4*)(weights + (size_t)(f0 + fslot) * WROW + (u * 4 + jo) * 8) = st;
}

// ---------------- Kernel 2: DPP segmented scan + pinned load batch ----------
// Lane mapping: lane = j*16 + e  (e = edge-in-group 0..15, j = out-quad 0..3).
// The 16 edges of a group occupy one 16-lane DPP row, so the segmented
// suffix scan runs entirely on the VALU (update_dpp row_shl), freeing the
// LDS pipe (only the 8 x-broadcast bpermutes per group remain).

template <int CTRL>
__device__ __forceinline__ int dpp_i(int old, int v) {
  return __builtin_amdgcn_update_dpp(old, v, CTRL, 0xf, 0xf, false);
}
template <int CTRL>
__device__ __forceinline__ float dpp_f(float v) {
  return __builtin_bit_cast(
      float, __builtin_amdgcn_update_dpp(0, __builtin_bit_cast(int, v), CTRL,
                                         0xf, 0xf, true));
}

template <int CTRL>
__device__ __forceinline__ void seg_step(int s, fvec4& acc, float& cnt) {
  const int os = dpp_i<CTRL>(-1, s);     // out-of-row -> -1 (never matches)
  const float ox = dpp_f<CTRL>(acc.x);
  const float oy = dpp_f<CTRL>(acc.y);
  const float oz = dpp_f<CTRL>(acc.z);
  const float ow = dpp_f<CTRL>(acc.w);
  const float oc = dpp_f<CTRL>(cnt);
  if (os == s) {
    acc.x += ox; acc.y += oy; acc.z += oz; acc.w += ow;
    cnt += oc;
  }
}

__device__ __forceinline__ void seg_reduce_flush(
    int s, fvec4 acc, float cnt, bool valid, int j,
    float* __restrict__ sums, float* __restrict__ deg) {
  if (!valid) {
    acc.x = 0.f; acc.y = 0.f; acc.z = 0.f; acc.w = 0.f;
    cnt = 0.f;
    s = -1;
  }
  // suffix Kogge-Stone over the 16-lane row: row_shl:N reads lane n+N.
  seg_step<0x101>(s, acc, cnt);
  seg_step<0x102>(s, acc, cnt);
  seg_step<0x104>(s, acc, cnt);
  seg_step<0x108>(s, acc, cnt);
  // head = prev lane (row_shr:1 reads lane n-1; row start -> -1) differs.
  const int ps = dpp_i<0x111>(-1, s);
  if (valid && ps != s) {
    float* p = sums + (size_t)s * OUT_CH + j * 4;
    atomicAdd(p + 0, acc.x);
    atomicAdd(p + 1, acc.y);
    atomicAdd(p + 2, acc.z);
    atomicAdd(p + 3, acc.w);
    if (j == 0) atomicAdd(deg + s, cnt);
  }
}

__device__ __forceinline__ fvec4 edge_dot16(const fvec4 xo, const uvec4* wv,
                                            int e16) {
  // pack own quarter (4 floats) into 2 f16 pairs; gather all 4 quarters of
  // this edge from lanes {e16, e16+16, e16+32, e16+48} via bpermute.
  const int p0 = (int)pk_f16(xo.x, xo.y);
  const int p1 = (int)pk_f16(xo.z, xo.w);
  half2_v xp[8];
  #pragma unroll
  for (int q = 0; q < 4; ++q) {
    xp[2 * q]     = __builtin_bit_cast(half2_v, __shfl(p0, e16 + (q << 4)));
    xp[2 * q + 1] = __builtin_bit_cast(half2_v, __shfl(p1, e16 + (q << 4)));
  }
  fvec4 acc = {0.f, 0.f, 0.f, 0.f};
  #pragma unroll
  for (int u = 0; u < 8; ++u) {
    acc.x = dot2(wv[u].x, xp[u], acc.x);
    acc.y = dot2(wv[u].y, xp[u], acc.y);
    acc.z = dot2(wv[u].z, xp[u], acc.z);
    acc.w = dot2(wv[u].w, xp[u], acc.w);
  }
  return acc;
}

__global__ __launch_bounds__(256)
__attribute__((amdgpu_waves_per_eu(4, 4)))
void edge_kernel(
    const float* __restrict__ input, const int* __restrict__ idxn,
    const int* __restrict__ idxe, const int* __restrict__ seg,
    const unsigned short* __restrict__ weights, float* __restrict__ sums,
    float* __restrict__ deg, int n_edges) {
  const int lane = threadIdx.x & 63;
  const int wib = threadIdx.x >> 6;
  const int e16 = lane & 15;   // edge within group (DPP row position)
  const int j = lane >> 4;     // output quad (row index)

  const long wbase = (long)blockIdx.x * 128 + wib * 32;
  long eA = wbase + e16;
  long eB = eA + 16;
  const bool vA = eA < n_edges;
  const bool vB = eB < n_edges;
  if (!vA) eA = n_edges - 1;
  if (!vB) eB = n_edges - 1;

  const int sA = seg[eA];
  const int nA = idxn[eA];
  const int fA = idxe[eA];
  const int sB = seg[eB];
  const int nB = idxn[eB];
  const int fB = idxe[eB];

  // Issue ALL 18 vector loads; the asm pin below forces them to be
  // materialized together (batched issue, single vmcnt drain).
  const fvec4 xoA = ((const fvec4*)(input + (size_t)nA * IN_CH))[j];
  const uvec4* __restrict__ wqA = (const uvec4*)(weights + (size_t)fA * WROW);
  uvec4 wvA[8];
  #pragma unroll
  for (int u = 0; u < 8; ++u) wvA[u] = wqA[u * 4 + j];
  const fvec4 xoB = ((const fvec4*)(input + (size_t)nB * IN_CH))[j];
  const uvec4* __restrict__ wqB = (const uvec4*)(weights + (size_t)fB * WROW);
  uvec4 wvB[8];
  #pragma unroll
  for (int u = 0; u < 8; ++u) wvB[u] = wqB[u * 4 + j];

  asm volatile("" ::
      "v"(wvA[0]), "v"(wvA[1]), "v"(wvA[2]), "v"(wvA[3]),
      "v"(wvA[4]), "v"(wvA[5]), "v"(wvA[6]), "v"(wvA[7]),
      "v"(wvB[0]), "v"(wvB[1]), "v"(wvB[2]), "v"(wvB[3]),
      "v"(wvB[4]), "v"(wvB[5]), "v"(wvB[6]), "v"(wvB[7]),
      "v"(xoA), "v"(xoB));

  const fvec4 accA = edge_dot16(xoA, wvA, e16);
  const fvec4 accB = edge_dot16(xoB, wvB, e16);

  seg_reduce_flush(sA, accA, 1.f, vA, j, sums, deg);
  seg_reduce_flush(sB, accB, 1.f, vB, j, sums, deg);
}

// ---------------- Kernel 3: divide by degree --------------------------------
__global__ __launch_bounds__(256) void finalize_kernel(
    const float* __restrict__ sums, const float* __restrict__ deg,
    float* __restrict__ out, int n_nodes) {
  const int n = blockIdx.x * blockDim.x + threadIdx.x;
  if (n >= n_nodes) return;
  const float d = deg[n];
  const float scale = d > 0.f ? 1.f / d : 0.f;
  const float4* sp = (const float4*)(sums + (size_t)n * OUT_CH);
  float4* op = (float4*)(out + (size_t)n * OUT_CH);
  #pragma unroll
  for (int q = 0; q < 4; ++q) {
    float4 v = sp[q];
    v.x *= scale; v.y *= scale; v.z *= scale; v.w *= scale;
    op[q] = v;
  }
}

extern "C" void kernel_launch(void* const* d_in, const int* in_sizes, int n_in,
                              void* d_out, int out_size, void* d_ws, size_t ws_size,
                              hipStream_t stream) {
  const float* input = (const float*)d_in[0];
  const int* idxn    = (const int*)d_in[1];
  const int* idxe    = (const int*)d_in[2];
  const int* seg     = (const int*)d_in[3];
  const float* ef    = (const float*)d_in[4];
  const float* W1    = (const float*)d_in[5];
  const float* b1    = (const float*)d_in[6];
  const float* W2    = (const float*)d_in[7];
  const float* b2    = (const float*)d_in[8];
  float* out = (float*)d_out;

  const int n_nodes   = in_sizes[0] / IN_CH;
  const int n_edges   = in_sizes[1];
  const int n_filters = in_sizes[4] / EDGE_FEAT;

  // workspace: f16 weights [F*256] (2 MB) | sums [n_nodes*16] | deg [n_nodes]
  unsigned short* weights = (unsigned short*)d_ws;
  float* sums = (float*)((char*)d_ws + (size_t)n_filters * WROW * sizeof(unsigned short));
  float* deg  = sums + (size_t)n_nodes * OUT_CH;

  // filter_net also zeroes sums|deg (contiguous region, float4-aligned).
  const int nzero4 = (n_nodes * (OUT_CH + 1)) / 4;
  filter_net_kernel<<<n_filters / FN_FPB, 256, 0, stream>>>(
      ef, W1, b1, W2, b2, weights, sums, nzero4);

  // 128 edges per 256-thread block (2 groups of 16 per wave).
  const long n_blocks = ((long)n_edges + 127) / 128;
  edge_kernel<<<(int)n_blocks, 256, 0, stream>>>(
      input, idxn, idxe, seg, weights, sums, deg, n_edges);

  finalize_kernel<<<(n_nodes + 255) / 256, 256, 0, stream>>>(sums, deg, out,
                                                             n_nodes);
}

// Round 10
// 160.425 us; speedup vs baseline: 1.2999x; 1.2999x over previous
//
#include <hip/hip_runtime.h>

#define IN_CH 16
#define OUT_CH 16
#define EDGE_FEAT 32
#define HIDDEN 128
#define WROW 256          // IN_CH*OUT_CH
#define FN_FPB 8          // filters per block in filter-net kernel

// f16 weight row layout (512 B): 32 chunks of 16 B.
// chunk (u*4 + j), u in [0,8), j in [0,4): dword c (c in [0,4)) holds the
// f16 pair ( w[2u][4j+c] , w[2u+1][4j+c] ) — pairs run along the input
// channel so one v_dot2_f32_f16 consumes both.
// Edge-quad lane j loads chunks {u*4+j}; a quad's load u is one 64 B line.

typedef __fp16 half2_v __attribute__((ext_vector_type(2)));
typedef unsigned uvec4 __attribute__((ext_vector_type(4)));
typedef float fvec4 __attribute__((ext_vector_type(4)));

__device__ __forceinline__ unsigned pk_f16(float lo, float hi) {
  half2_v h = __builtin_amdgcn_cvt_pkrtz(lo, hi);
  return __builtin_bit_cast(unsigned, h);
}

__device__ __forceinline__ float dot2(unsigned wpair, half2_v xp, float acc) {
  half2_v w = __builtin_bit_cast(half2_v, wpair);
#if __has_builtin(__builtin_amdgcn_fdot2)
  return __builtin_amdgcn_fdot2(xp, w, acc, false);
#else
  acc = fmaf((float)xp[0], (float)w[0], acc);
  return fmaf((float)xp[1], (float)w[1], acc);
#endif
}

// ---------------- Kernel 1: filter net (f16 pair-layout output) -------------
__global__ __launch_bounds__(256) void filter_net_kernel(
    const float* __restrict__ ef, const float* __restrict__ W1,
    const float* __restrict__ b1, const float* __restrict__ W2,
    const float* __restrict__ b2, unsigned short* __restrict__ weights,
    float* __restrict__ zero_base, int nzero4) {
  const int t = threadIdx.x;
  const int f0 = blockIdx.x * FN_FPB;

  // fused zeroing of sums+deg
  for (int gid = blockIdx.x * 256 + t; gid < nzero4; gid += gridDim.x * 256)
    ((float4*)zero_base)[gid] = make_float4(0.f, 0.f, 0.f, 0.f);

  __shared__ float ef_s[FN_FPB * EDGE_FEAT];  // 256 floats
  __shared__ float h_s[FN_FPB][HIDDEN];       // 1024 floats
  ef_s[t] = ef[f0 * EDGE_FEAT + t];
  __syncthreads();

  // stage 1: 1024 h values, 4 per thread.
  #pragma unroll
  for (int r = 0; r < 4; ++r) {
    const int idx = t + r * 256;
    const int fi = idx >> 7;
    const int hi = idx & (HIDDEN - 1);
    float a = b1[hi];
    #pragma unroll
    for (int k = 0; k < EDGE_FEAT; ++k)
      a = fmaf(ef_s[fi * EDGE_FEAT + k], W1[k * HIDDEN + hi], a);
    h_s[fi][hi] = a > 0.f ? a : 0.f;
  }
  __syncthreads();

  const int fslot = t >> 5;
  const int combo = t & 31;
  const int u = combo >> 2;
  const int jo = combo & 3;
  const int colLo = 32 * u + 4 * jo;   // out col base for i = 2u
  const int colHi = colLo + 16;        // for i = 2u+1

  float4 aLo = *(const float4*)(b2 + colLo);
  float4 aHi = *(const float4*)(b2 + colHi);
  const float* __restrict__ hrow = h_s[fslot];
  #pragma unroll 4
  for (int k = 0; k < HIDDEN; ++k) {
    const float4 wLo = *(const float4*)(W2 + (size_t)k * WROW + colLo);
    const float4 wHi = *(const float4*)(W2 + (size_t)k * WROW + colHi);
    const float hv = hrow[k];
    aLo.x = fmaf(hv, wLo.x, aLo.x);
    aLo.y = fmaf(hv, wLo.y, aLo.y);
    aLo.z = fmaf(hv, wLo.z, aLo.z);
    aLo.w = fmaf(hv, wLo.w, aLo.w);
    aHi.x = fmaf(hv, wHi.x, aHi.x);
    aHi.y = fmaf(hv, wHi.y, aHi.y);
    aHi.z = fmaf(hv, wHi.z, aHi.z);
    aHi.w = fmaf(hv, wHi.w, aHi.w);
  }

  uint4 st;
  st.x = pk_f16(aLo.x, aHi.x);
  st.y = pk_f16(aLo.y, aHi.y);
  st.z = pk_f16(aLo.z, aHi.z);
  st.w = pk_f16(aLo.w, aHi.w);
  *(uint4*)(weights + (size_t)(f0 + fslot) * WROW + (u * 4 + jo) * 8) = st;
}

// ---------------- Kernel 2: r8 layout + DPP-based segmented reduce ----------
// Lane = e16*4 + j (e16 = edge in group, j = out-quad) — quad-coalesced loads.
// Each 16-lane DPP row holds exactly 4 edges, so scan distances of 1-2 edges
// (4/8 lanes) run on the VALU via row_shl; distances 4/8 edges combine
// row-head partials via bpermute. DS ops/wave: 78 (r8) -> 26.

template <int CTRL, int OLD>
__device__ __forceinline__ int dpp_i(int v) {
  return __builtin_amdgcn_update_dpp(OLD, v, CTRL, 0xf, 0xf, false);
}
template <int CTRL>
__device__ __forceinline__ float dpp_f(float v) {
  return __builtin_bit_cast(
      float, __builtin_amdgcn_update_dpp(0, __builtin_bit_cast(int, v), CTRL,
                                         0xf, 0xf, false));
}
// quad_perm broadcast of quad-lane Q: ctrl = Q*0x55
template <int Q>
__device__ __forceinline__ int quad_bcast_dpp(int v) {
  return __builtin_amdgcn_update_dpp(0, v, Q * 0x55, 0xf, 0xf, false);
}

// phase-1 scan step (within 16-lane row = 4 edges); CTRL=0x104 (+1 edge),
// 0x108 (+2 edges). Shifted-out lanes: s -> -1 (no match), floats -> 0.
template <int CTRL>
__device__ __forceinline__ void seg_step_dpp(int s, fvec4& acc, float& cnt) {
  const int os = dpp_i<CTRL, -1>(s);
  const float ox = dpp_f<CTRL>(acc.x);
  const float oy = dpp_f<CTRL>(acc.y);
  const float oz = dpp_f<CTRL>(acc.z);
  const float ow = dpp_f<CTRL>(acc.w);
  const float oc = dpp_f<CTRL>(cnt);
  if (os == s) {
    acc.x += ox; acc.y += oy; acc.z += oz; acc.w += ow;
    cnt += oc;
  }
}

// phase-2 step: pull row-head partial from row r+d (src = 16(r+d)+j).
__device__ __forceinline__ void seg_step_bperm(int src, int s, fvec4& acc,
                                               float& cnt) {
  const int os = __shfl(s, src & 63);
  const float ox = __shfl(acc.x, src & 63);
  const float oy = __shfl(acc.y, src & 63);
  const float oz = __shfl(acc.z, src & 63);
  const float ow = __shfl(acc.w, src & 63);
  const float oc = __shfl(cnt, src & 63);
  if (src < 64 && os == s) {
    acc.x += ox; acc.y += oy; acc.z += oz; acc.w += ow;
    cnt += oc;
  }
}

__device__ __forceinline__ void seg_reduce_flush(
    int s, fvec4 acc, float cnt, bool valid, int lane, int e16, int j,
    float* __restrict__ sums, float* __restrict__ deg) {
  if (!valid) {
    acc.x = 0.f; acc.y = 0.f; acc.z = 0.f; acc.w = 0.f;
    cnt = 0.f;
    s = -1;
  }
  // phase 1: suffix scan within row (4 edges), VALU only.
  seg_step_dpp<0x104>(s, acc, cnt);   // + edge e+1
  seg_step_dpp<0x108>(s, acc, cnt);   // + edges e+2,e+3
  // phase 2: combine row-head partials across rows (Kogge-Stone over rows).
  const int rb = (lane & ~15) | (lane & 3);   // 16*r + j
  seg_step_bperm(rb + 16, s, acc, cnt);       // + next row
  seg_step_bperm(rb + 32, s, acc, cnt);       // + rows r+2, r+3
  // head-of-run test (prev edge = lane-4; group start always flushes).
  const int ps = __shfl(s, (lane - 4) & 63);
  const bool head = (e16 == 0) || (ps != s);
  if (valid && head && s >= 0) {
    float* p = sums + (size_t)s * OUT_CH + j * 4;
    atomicAdd(p + 0, acc.x);
    atomicAdd(p + 1, acc.y);
    atomicAdd(p + 2, acc.z);
    atomicAdd(p + 3, acc.w);
    if (j == 0) atomicAdd(deg + s, cnt);
  }
}

__device__ __forceinline__ fvec4 edge_dot(const fvec4 xo, const uvec4* wv) {
  // pack own quarter into 2 f16 pairs; broadcast quarters via DPP quad_perm.
  const int p0 = (int)pk_f16(xo.x, xo.y);
  const int p1 = (int)pk_f16(xo.z, xo.w);
  half2_v xp[8];
  xp[0] = __builtin_bit_cast(half2_v, quad_bcast_dpp<0>(p0));
  xp[1] = __builtin_bit_cast(half2_v, quad_bcast_dpp<0>(p1));
  xp[2] = __builtin_bit_cast(half2_v, quad_bcast_dpp<1>(p0));
  xp[3] = __builtin_bit_cast(half2_v, quad_bcast_dpp<1>(p1));
  xp[4] = __builtin_bit_cast(half2_v, quad_bcast_dpp<2>(p0));
  xp[5] = __builtin_bit_cast(half2_v, quad_bcast_dpp<2>(p1));
  xp[6] = __builtin_bit_cast(half2_v, quad_bcast_dpp<3>(p0));
  xp[7] = __builtin_bit_cast(half2_v, quad_bcast_dpp<3>(p1));

  fvec4 acc = {0.f, 0.f, 0.f, 0.f};
  #pragma unroll
  for (int u = 0; u < 8; ++u) {
    acc.x = dot2(wv[u].x, xp[u], acc.x);
    acc.y = dot2(wv[u].y, xp[u], acc.y);
    acc.z = dot2(wv[u].z, xp[u], acc.z);
    acc.w = dot2(wv[u].w, xp[u], acc.w);
  }
  return acc;
}

__global__ __launch_bounds__(256, 4) void edge_kernel(
    const float* __restrict__ input, const int* __restrict__ idxn,
    const int* __restrict__ idxe, const int* __restrict__ seg,
    const unsigned short* __restrict__ weights, float* __restrict__ sums,
    float* __restrict__ deg, int n_edges) {
  const int lane = threadIdx.x & 63;
  const int wib = threadIdx.x >> 6;
  const int e16 = lane >> 2;   // edge within group
  const int j = lane & 3;      // output quad (quad-coalesced loads)

  const long wbase = (long)blockIdx.x * 128 + wib * 32;
  long eA = wbase + e16;
  long eB = eA + 16;
  const bool vA = eA < n_edges;
  const bool vB = eB < n_edges;
  if (!vA) eA = n_edges - 1;
  if (!vB) eB = n_edges - 1;

  const int sA = seg[eA];
  const int nA = idxn[eA];
  const int fA = idxe[eA];
  const int sB = seg[eB];
  const int nB = idxn[eB];
  const int fB = idxe[eB];

  // Issue ALL 18 vector loads before any compute/flush.
  const fvec4 xoA = ((const fvec4*)(input + (size_t)nA * IN_CH))[j];
  const uvec4* __restrict__ wqA = (const uvec4*)(weights + (size_t)fA * WROW);
  uvec4 wvA[8];
  #pragma unroll
  for (int u = 0; u < 8; ++u) wvA[u] = wqA[u * 4 + j];
  const fvec4 xoB = ((const fvec4*)(input + (size_t)nB * IN_CH))[j];
  const uvec4* __restrict__ wqB = (const uvec4*)(weights + (size_t)fB * WROW);
  uvec4 wvB[8];
  #pragma unroll
  for (int u = 0; u < 8; ++u) wvB[u] = wqB[u * 4 + j];

  const fvec4 accA = edge_dot(xoA, wvA);
  const fvec4 accB = edge_dot(xoB, wvB);

  seg_reduce_flush(sA, accA, 1.f, vA, lane, e16, j, sums, deg);
  seg_reduce_flush(sB, accB, 1.f, vB, lane, e16, j, sums, deg);
}

// ---------------- Kernel 3: divide by degree --------------------------------
__global__ __launch_bounds__(256) void finalize_kernel(
    const float* __restrict__ sums, const float* __restrict__ deg,
    float* __restrict__ out, int n_nodes) {
  const int n = blockIdx.x * blockDim.x + threadIdx.x;
  if (n >= n_nodes) return;
  const float d = deg[n];
  const float scale = d > 0.f ? 1.f / d : 0.f;
  const float4* sp = (const float4*)(sums + (size_t)n * OUT_CH);
  float4* op = (float4*)(out + (size_t)n * OUT_CH);
  #pragma unroll
  for (int q = 0; q < 4; ++q) {
    float4 v = sp[q];
    v.x *= scale; v.y *= scale; v.z *= scale; v.w *= scale;
    op[q] = v;
  }
}

extern "C" void kernel_launch(void* const* d_in, const int* in_sizes, int n_in,
                              void* d_out, int out_size, void* d_ws, size_t ws_size,
                              hipStream_t stream) {
  const float* input = (const float*)d_in[0];
  const int* idxn    = (const int*)d_in[1];
  const int* idxe    = (const int*)d_in[2];
  const int* seg     = (const int*)d_in[3];
  const float* ef    = (const float*)d_in[4];
  const float* W1    = (const float*)d_in[5];
  const float* b1    = (const float*)d_in[6];
  const float* W2    = (const float*)d_in[7];
  const float* b2    = (const float*)d_in[8];
  float* out = (float*)d_out;

  const int n_nodes   = in_sizes[0] / IN_CH;
  const int n_edges   = in_sizes[1];
  const int n_filters = in_sizes[4] / EDGE_FEAT;

  // workspace: f16 weights [F*256] (2 MB) | sums [n_nodes*16] | deg [n_nodes]
  unsigned short* weights = (unsigned short*)d_ws;
  float* sums = (float*)((char*)d_ws + (size_t)n_filters * WROW * sizeof(unsigned short));
  float* deg  = sums + (size_t)n_nodes * OUT_CH;

  // filter_net also zeroes sums|deg (contiguous region, float4-aligned).
  const int nzero4 = (n_nodes * (OUT_CH + 1)) / 4;
  filter_net_kernel<<<n_filters / FN_FPB, 256, 0, stream>>>(
      ef, W1, b1, W2, b2, weights, sums, nzero4);

  // 128 edges per 256-thread block (2 groups of 16 per wave).
  const long n_blocks = ((long)n_edges + 127) / 128;
  edge_kernel<<<(int)n_blocks, 256, 0, stream>>>(
      input, idxn, idxe, seg, weights, sums, deg, n_edges);

  finalize_kernel<<<(n_nodes + 255) / 256, 256, 0, stream>>>(sums, deg, out,
                                                             n_nodes);
}